// Round 1
// baseline (378.711 us; speedup 1.0000x reference)
//
#include <hip/hip_runtime.h>
#include <hip/hip_bf16.h>

// Problem constants
constexpr int Bc = 32, Sc = 4096, Dc = 64, Pc = 8, STRIDEc = 4, Hc = 512;
constexpr int Tc = (Sc - Pc) / STRIDEc + 1;   // 1023
constexpr int Kc = Pc * Dc;                   // 512
constexpr float EPSc = 1e-6f;

__device__ __forceinline__ int n_tok_of(int len) {
    return (len >= Pc) ? ((len - Pc) / STRIDEc + 1) : 1;
}

// ---------------------------------------------------------------------------
// Kernel 1: tokens output + token_lengths.
// tokens[b,t,:] = x[b, t*STRIDE*D : t*STRIDE*D + P*D]  (contiguous slice),
// zeroed where t >= n_tok[b] (pos<len check kept for exactness).
// ---------------------------------------------------------------------------
__global__ __launch_bounds__(256) void tokens_kernel(
        const float* __restrict__ x, const int* __restrict__ lengths,
        float* __restrict__ out_tokens, float* __restrict__ out_tl) {
    const int idx = blockIdx.x * 256 + threadIdx.x;   // one float4 per thread
    const int row = idx >> 7;          // B*T rows
    const int c4  = idx & 127;         // 128 float4 per row
    const int b = row / Tc;
    const int t = row - b * Tc;
    const int len = lengths[b];
    const int n_tok = n_tok_of(len);
    const int p = c4 >> 4;             // patch index of this float4
    const int pos = t * STRIDEc + p;
    const bool valid = (t < n_tok) && (pos < len);

    float4 v = make_float4(0.f, 0.f, 0.f, 0.f);
    if (valid) {
        v = *(const float4*)(x + (size_t)b * Sc * Dc + (size_t)t * (STRIDEc * Dc) + c4 * 4);
    }
    *(float4*)(out_tokens + (size_t)row * Kc + c4 * 4) = v;

    if (blockIdx.x == 0 && threadIdx.x < Bc) {
        out_tl[threadIdx.x] = (float)n_tok_of(lengths[threadIdx.x]);
    }
}

// ---------------------------------------------------------------------------
// Kernel 2: h = tokens @ W + bias  (pre-norm), written into hidden region.
// fp32 tiled GEMM: BM=64, BN=64, BK=32, 256 threads, 4x4 microtile/thread.
// A is read directly from x (tokens rows are contiguous x slices).
// ---------------------------------------------------------------------------
__global__ __launch_bounds__(256) void gemm_kernel(
        const float* __restrict__ x, const int* __restrict__ lengths,
        const float* __restrict__ W, const float* __restrict__ bias,
        float* __restrict__ h_out) {
    const int n0 = blockIdx.x * 64;    // 8 n-tiles
    const int t0 = blockIdx.y * 64;    // 16 m-tiles (covers 1023 rows)
    const int b  = blockIdx.z;         // 32 batches
    const int len = lengths[b];
    const int n_tok = n_tok_of(len);

    __shared__ float As[32 * 68];      // transposed: As[k][r], row pad 68 (272B, 16B-aligned)
    __shared__ float Bs[32 * 64];      // Bs[k][n]

    const int tid = threadIdx.x;
    const int tx = tid & 15;           // col group (4 cols)
    const int ty = tid >> 4;           // row group (4 rows)

    float acc[4][4];
#pragma unroll
    for (int i = 0; i < 4; ++i)
#pragma unroll
        for (int j = 0; j < 4; ++j) acc[i][j] = 0.f;

    const float* xb = x + (size_t)b * Sc * Dc;

    for (int k0 = 0; k0 < Kc; k0 += 32) {
        // Stage A (64 rows x 32 k) transposed into LDS
#pragma unroll
        for (int it = 0; it < 2; ++it) {
            const int l = tid + it * 256;       // 0..511 float4 slots
            const int r = l >> 3;               // row in tile
            const int k = (l & 7) * 4;          // k offset in tile
            const int t = t0 + r;
            const int p = (k0 + k) >> 6;
            const int pos = t * STRIDEc + p;
            float4 v = make_float4(0.f, 0.f, 0.f, 0.f);
            if (t < Tc && t < n_tok && pos < len) {
                v = *(const float4*)(xb + (size_t)t * (STRIDEc * Dc) + k0 + k);
            }
            As[(k + 0) * 68 + r] = v.x;
            As[(k + 1) * 68 + r] = v.y;
            As[(k + 2) * 68 + r] = v.z;
            As[(k + 3) * 68 + r] = v.w;
        }
        // Stage B (32 k x 64 n)
#pragma unroll
        for (int it = 0; it < 2; ++it) {
            const int l = tid + it * 256;
            const int k = l >> 4;
            const int n = (l & 15) * 4;
            float4 w = *(const float4*)(W + (size_t)(k0 + k) * Hc + n0 + n);
            *(float4*)(Bs + k * 64 + n) = w;
        }
        __syncthreads();

#pragma unroll
        for (int k = 0; k < 32; ++k) {
            float4 a4 = *(const float4*)(As + k * 68 + ty * 4);
            float4 w4 = *(const float4*)(Bs + k * 64 + tx * 4);
            const float av[4] = {a4.x, a4.y, a4.z, a4.w};
            const float wv[4] = {w4.x, w4.y, w4.z, w4.w};
#pragma unroll
            for (int i = 0; i < 4; ++i)
#pragma unroll
                for (int j = 0; j < 4; ++j) acc[i][j] += av[i] * wv[j];
        }
        __syncthreads();
    }

    // Epilogue: + bias, store pre-norm h
    const float4 bv = *(const float4*)(bias + n0 + tx * 4);
#pragma unroll
    for (int i = 0; i < 4; ++i) {
        const int t = t0 + ty * 4 + i;
        if (t < Tc) {
            float4 o;
            o.x = acc[i][0] + bv.x;
            o.y = acc[i][1] + bv.y;
            o.z = acc[i][2] + bv.z;
            o.w = acc[i][3] + bv.w;
            *(float4*)(h_out + ((size_t)b * Tc + t) * Hc + n0 + tx * 4) = o;
        }
    }
}

// ---------------------------------------------------------------------------
// Kernel 3: in-place RMSNorm * scale. One wave (64 lanes) per row of 512.
// ---------------------------------------------------------------------------
__global__ __launch_bounds__(256) void rms_kernel(
        float* __restrict__ h, const float* __restrict__ scale) {
    const int m = blockIdx.x * 4 + (threadIdx.x >> 6);   // row index, B*T total
    const int lane = threadIdx.x & 63;
    float4* row = (float4*)(h + (size_t)m * Hc);
    const float4* s4 = (const float4*)scale;

    float4 v0 = row[lane];
    float4 v1 = row[lane + 64];
    float ss = v0.x * v0.x + v0.y * v0.y + v0.z * v0.z + v0.w * v0.w
             + v1.x * v1.x + v1.y * v1.y + v1.z * v1.z + v1.w * v1.w;
#pragma unroll
    for (int off = 32; off >= 1; off >>= 1) ss += __shfl_xor(ss, off);

    const float rms = sqrtf(ss * (1.0f / (float)Hc) + EPSc);
    const float inv = 1.0f / rms;

    float4 s0 = s4[lane];
    float4 s1 = s4[lane + 64];
    v0.x = v0.x * inv * s0.x; v0.y = v0.y * inv * s0.y;
    v0.z = v0.z * inv * s0.z; v0.w = v0.w * inv * s0.w;
    v1.x = v1.x * inv * s1.x; v1.y = v1.y * inv * s1.y;
    v1.z = v1.z * inv * s1.z; v1.w = v1.w * inv * s1.w;
    row[lane] = v0;
    row[lane + 64] = v1;
}

extern "C" void kernel_launch(void* const* d_in, const int* in_sizes, int n_in,
                              void* d_out, int out_size, void* d_ws, size_t ws_size,
                              hipStream_t stream) {
    const float* x       = (const float*)d_in[0];
    const int*   lengths = (const int*)d_in[1];
    const float* W       = (const float*)d_in[2];
    const float* bias    = (const float*)d_in[3];
    const float* scale   = (const float*)d_in[4];

    const size_t BTH = (size_t)Bc * Tc * Hc;   // 16,760,832
    float* out    = (float*)d_out;
    float* hidden = out;                        // output 0
    float* tl     = out + BTH;                  // output 1 (32 floats)
    float* tokens = out + BTH + Bc;             // output 2

    // Kernel 1: tokens + token_lengths. B*T*128 float4 = 4,190,208 threads.
    {
        const int total = Bc * Tc * 128;
        tokens_kernel<<<total / 256, 256, 0, stream>>>(x, lengths, tokens, tl);
    }
    // Kernel 2: GEMM -> pre-norm h in hidden region.
    {
        dim3 grid(Hc / 64, (Tc + 63) / 64, Bc);   // (8, 16, 32)
        gemm_kernel<<<grid, 256, 0, stream>>>(x, lengths, W, bias, hidden);
    }
    // Kernel 3: in-place RMSNorm. B*T rows, 4 rows/block.
    {
        const int rows = Bc * Tc;                 // 32736, divisible by 4
        rms_kernel<<<rows / 4, 256, 0, stream>>>(hidden, scale);
    }
}

// Round 2
// 198.831 us; speedup vs baseline: 1.9047x; 1.9047x over previous
//
#include <hip/hip_runtime.h>
#include <hip/hip_bf16.h>

// Problem constants
constexpr int Bc = 32, Sc = 4096, Dc = 64, Pc = 8, STRIDEc = 4, Hc = 512;
constexpr int Tc = (Sc - Pc) / STRIDEc + 1;   // 1023
constexpr int Kc = Pc * Dc;                   // 512
constexpr float EPSc = 1e-6f;
constexpr int PITCH = 40;                     // bf16 LDS row pitch (80B: 2-way banks = free)

typedef __bf16 bf16x8 __attribute__((ext_vector_type(8)));
typedef unsigned short ushort8 __attribute__((ext_vector_type(8)));
typedef float f32x4 __attribute__((ext_vector_type(4)));

__device__ __forceinline__ int n_tok_of(int len) {
    return (len >= Pc) ? ((len - Pc) / STRIDEc + 1) : 1;
}

// fp32 -> bf16 round-to-nearest-even
__device__ __forceinline__ unsigned short f2bf(float f) {
    unsigned u = __builtin_bit_cast(unsigned, f);
    u = (u + 0x7FFFu + ((u >> 16) & 1u)) >> 16;
    return (unsigned short)u;
}

// ---------------------------------------------------------------------------
// Prep: Wt[n][k] = bf16(W[k][n])  (transposed, rounded), + token_lengths out.
// grid (16,16) tiles of 32x32, 256 threads.
// ---------------------------------------------------------------------------
__global__ __launch_bounds__(256) void prep_kernel(
        const float* __restrict__ W, const int* __restrict__ lengths,
        unsigned short* __restrict__ Wt, float* __restrict__ out_tl) {
    __shared__ float tile[32][33];
    const int k0 = blockIdx.x * 32, n0 = blockIdx.y * 32;
    const int r = threadIdx.x >> 3, c = (threadIdx.x & 7) * 4;
    const float4 v = *(const float4*)(W + (size_t)(k0 + r) * Hc + n0 + c);
    tile[c + 0][r] = v.x;
    tile[c + 1][r] = v.y;
    tile[c + 2][r] = v.z;
    tile[c + 3][r] = v.w;
    __syncthreads();
    ushort4 o;
    o.x = f2bf(tile[r][c + 0]);
    o.y = f2bf(tile[r][c + 1]);
    o.z = f2bf(tile[r][c + 2]);
    o.w = f2bf(tile[r][c + 3]);
    *(ushort4*)(Wt + (size_t)(n0 + r) * Kc + k0 + c) = o;
    if (blockIdx.x == 0 && blockIdx.y == 0 && threadIdx.x < Bc)
        out_tl[threadIdx.x] = (float)n_tok_of(lengths[threadIdx.x]);
}

// ---------------------------------------------------------------------------
// Fused: tokens-write + bf16-MFMA GEMM (BM=64 x BN=512) + bias + RMSNorm*scale.
// 256 threads = 4 waves; wave w owns cols [128w, 128w+128): 4 m-tiles x 8 n-tiles
// of 16x16x32 MFMA, acc = 128 VGPRs/lane.
// ---------------------------------------------------------------------------
__global__ __launch_bounds__(256, 2) void fused_kernel(
        const float* __restrict__ x, const int* __restrict__ lengths,
        const unsigned short* __restrict__ Wt, const float* __restrict__ bias,
        const float* __restrict__ scale, float* __restrict__ hidden,
        float* __restrict__ tokens) {
    const int b  = blockIdx.y;
    const int t0 = blockIdx.x * 64;
    const int len = lengths[b];
    const int ntok = n_tok_of(len);

    __shared__ unsigned short As[64 * PITCH];    // As[r][k], bf16
    __shared__ unsigned short Bs[512 * PITCH];   // Bs[n][k], bf16 (Wt tile)
    __shared__ float ssbuf[4][64];
    __shared__ float rstd[64];

    const int tid  = threadIdx.x;
    const int w    = tid >> 6;
    const int lane = tid & 63;
    const int l15  = lane & 15;
    const int quad = lane >> 4;

    f32x4 acc[4][8];
#pragma unroll
    for (int mt = 0; mt < 4; ++mt)
#pragma unroll
        for (int nt = 0; nt < 8; ++nt) acc[mt][nt] = (f32x4){0.f, 0.f, 0.f, 0.f};

    const float* xb   = x + (size_t)b * (Sc * Dc);
    float*       tokb = tokens + (size_t)b * Tc * Kc;

    for (int k0 = 0; k0 < Kc; k0 += 32) {
        if (k0) __syncthreads();
        // ---- stage A (64 rows x 32 k) from x, emit tokens, bf16 into LDS ----
#pragma unroll
        for (int it = 0; it < 2; ++it) {
            const int l = tid + it * 256;         // 512 float4 chunks
            const int r = l >> 3;                 // row in tile
            const int c = l & 7;                  // float4 index within 32-k
            const int t = t0 + r;
            const int kk = k0 + c * 4;
            const int p = kk >> 6;
            const int pos = t * STRIDEc + p;
            const bool tval = (t < Tc);
            float4 v = make_float4(0.f, 0.f, 0.f, 0.f);
            if (tval && t < ntok && pos < len)
                v = *(const float4*)(xb + (size_t)t * (STRIDEc * Dc) + kk);
            if (tval)
                *(float4*)(tokb + (size_t)t * Kc + kk) = v;
            ushort4 h4;
            h4.x = f2bf(v.x); h4.y = f2bf(v.y); h4.z = f2bf(v.z); h4.w = f2bf(v.w);
            *(ushort4*)(As + r * PITCH + c * 4) = h4;
        }
        // ---- stage B (512 n x 32 k) from Wt bf16 ----
#pragma unroll
        for (int it = 0; it < 8; ++it) {
            const int cc = tid + it * 256;        // 2048 chunks of 8 bf16
            const int n  = cc >> 2;
            const int ko = (cc & 3) * 8;
            ushort8 v = *(const ushort8*)(Wt + (size_t)n * Kc + k0 + ko);
            *(ushort8*)(Bs + n * PITCH + ko) = v;
        }
        __syncthreads();
        // ---- MFMA ----
        bf16x8 af[4];
#pragma unroll
        for (int mt = 0; mt < 4; ++mt)
            af[mt] = __builtin_bit_cast(bf16x8,
                *(const ushort8*)(As + (mt * 16 + l15) * PITCH + quad * 8));
#pragma unroll
        for (int nt = 0; nt < 8; ++nt) {
            bf16x8 bfrag = __builtin_bit_cast(bf16x8,
                *(const ushort8*)(Bs + (w * 128 + nt * 16 + l15) * PITCH + quad * 8));
#pragma unroll
            for (int mt = 0; mt < 4; ++mt)
                acc[mt][nt] = __builtin_amdgcn_mfma_f32_16x16x32_bf16(
                    af[mt], bfrag, acc[mt][nt], 0, 0, 0);
        }
    }

    // ---- epilogue: bias, row sum-of-squares, RMS, scale, store ----
    float ss[4][4];
#pragma unroll
    for (int mt = 0; mt < 4; ++mt)
#pragma unroll
        for (int rg = 0; rg < 4; ++rg) ss[mt][rg] = 0.f;

#pragma unroll
    for (int nt = 0; nt < 8; ++nt) {
        const float bv = bias[w * 128 + nt * 16 + l15];
#pragma unroll
        for (int mt = 0; mt < 4; ++mt)
#pragma unroll
            for (int rg = 0; rg < 4; ++rg) {
                float h = acc[mt][nt][rg] + bv;
                acc[mt][nt][rg] = h;
                ss[mt][rg] += h * h;
            }
    }
#pragma unroll
    for (int mt = 0; mt < 4; ++mt)
#pragma unroll
        for (int rg = 0; rg < 4; ++rg) {
            float s = ss[mt][rg];
            s += __shfl_xor(s, 1);
            s += __shfl_xor(s, 2);
            s += __shfl_xor(s, 4);
            s += __shfl_xor(s, 8);
            if (l15 == 0) ssbuf[w][mt * 16 + quad * 4 + rg] = s;
        }
    __syncthreads();
    if (tid < 64) {
        const float s = ssbuf[0][tid] + ssbuf[1][tid] + ssbuf[2][tid] + ssbuf[3][tid];
        rstd[tid] = rsqrtf(s * (1.0f / (float)Hc) + EPSc);
    }
    __syncthreads();

#pragma unroll
    for (int nt = 0; nt < 8; ++nt) {
        const int col = w * 128 + nt * 16 + l15;
        const float sv = scale[col];
#pragma unroll
        for (int mt = 0; mt < 4; ++mt)
#pragma unroll
            for (int rg = 0; rg < 4; ++rg) {
                const int rblk = mt * 16 + quad * 4 + rg;
                const int t = t0 + rblk;
                if (t < Tc)
                    hidden[((size_t)b * Tc + t) * Hc + col] =
                        acc[mt][nt][rg] * rstd[rblk] * sv;
            }
    }
}

extern "C" void kernel_launch(void* const* d_in, const int* in_sizes, int n_in,
                              void* d_out, int out_size, void* d_ws, size_t ws_size,
                              hipStream_t stream) {
    const float* x       = (const float*)d_in[0];
    const int*   lengths = (const int*)d_in[1];
    const float* W       = (const float*)d_in[2];
    const float* bias    = (const float*)d_in[3];
    const float* scale   = (const float*)d_in[4];

    const size_t BTH = (size_t)Bc * Tc * Hc;   // 16,760,832
    float* out    = (float*)d_out;
    float* hidden = out;                        // output 0
    float* tl     = out + BTH;                  // output 1 (32 floats)
    float* tokens = out + BTH + Bc;             // output 2

    unsigned short* Wt = (unsigned short*)d_ws; // 512x512 bf16 = 512 KB

    {   // W -> Wt (transpose + bf16) and token_lengths
        dim3 grid(Hc / 32, Hc / 32);            // (16,16)
        prep_kernel<<<grid, 256, 0, stream>>>(W, lengths, Wt, tl);
    }
    {   // fused tokens + GEMM + RMSNorm
        dim3 grid(16, Bc);                      // 16 m-blocks x 32 batches
        fused_kernel<<<grid, 256, 0, stream>>>(x, lengths, Wt, bias, scale,
                                               hidden, tokens);
    }
}

// Round 3
// 181.861 us; speedup vs baseline: 2.0824x; 1.0933x over previous
//
#include <hip/hip_runtime.h>
#include <hip/hip_bf16.h>

// Problem constants
constexpr int Bc = 32, Sc = 4096, Dc = 64, Pc = 8, STRIDEc = 4, Hc = 512;
constexpr int Tc = (Sc - Pc) / STRIDEc + 1;   // 1023
constexpr int Kc = Pc * Dc;                   // 512
constexpr float EPSc = 1e-6f;
constexpr int PITCH = 40;                     // bf16 LDS row pitch (80B -> 2-way banks = free)

typedef __bf16 bf16x8 __attribute__((ext_vector_type(8)));
typedef unsigned short ushort8 __attribute__((ext_vector_type(8)));
typedef float f32x4 __attribute__((ext_vector_type(4)));

__device__ __forceinline__ int n_tok_of(int len) {
    return (len >= Pc) ? ((len - Pc) / STRIDEc + 1) : 1;
}

// fp32 -> bf16 round-to-nearest-even
__device__ __forceinline__ unsigned short f2bf(float f) {
    unsigned u = __builtin_bit_cast(unsigned, f);
    u = (u + 0x7FFFu + ((u >> 16) & 1u)) >> 16;
    return (unsigned short)u;
}

// ---------------------------------------------------------------------------
// Prep: Wt_s[k0/32][n][k%32] = bf16(W[k][n])  (transposed, k-slice-packed so
// each k-step's B tile is one contiguous 32 KB block), + token_lengths.
// grid (16,16) tiles of 32x32, 256 threads.
// ---------------------------------------------------------------------------
__global__ __launch_bounds__(256) void prep_kernel(
        const float* __restrict__ W, const int* __restrict__ lengths,
        unsigned short* __restrict__ Wt, float* __restrict__ out_tl) {
    __shared__ float tile[32][33];
    const int k0 = blockIdx.x * 32, n0 = blockIdx.y * 32;
    const int r = threadIdx.x >> 3, c = (threadIdx.x & 7) * 4;
    const float4 v = *(const float4*)(W + (size_t)(k0 + r) * Hc + n0 + c);
    tile[c + 0][r] = v.x;
    tile[c + 1][r] = v.y;
    tile[c + 2][r] = v.z;
    tile[c + 3][r] = v.w;
    __syncthreads();
    ushort4 o;
    o.x = f2bf(tile[r][c + 0]);
    o.y = f2bf(tile[r][c + 1]);
    o.z = f2bf(tile[r][c + 2]);
    o.w = f2bf(tile[r][c + 3]);
    // slice = blockIdx.x; within slice: n-major, 32 k's per row
    *(ushort4*)(Wt + (size_t)blockIdx.x * (Hc * 32) + (size_t)(n0 + r) * 32 + c) = o;
    if (blockIdx.x == 0 && blockIdx.y == 0 && threadIdx.x < Bc)
        out_tl[threadIdx.x] = (float)n_tok_of(lengths[threadIdx.x]);
}

// ---------------------------------------------------------------------------
// Fused: tokens-write + bf16-MFMA GEMM (BM=64 x BN=512) + bias + RMSNorm*scale.
// 256 threads = 4 waves; wave w owns h-cols [128w, 128w+128).
// Operand-swapped MFMA: D^T layout -> lane l15 = token row, quad*4+reg = 4
// consecutive h-cols -> float4 epilogue stores + in-register RMS sums.
// Software-pipelined: next tile's global loads issued before the MFMA section.
// ---------------------------------------------------------------------------
__global__ __launch_bounds__(256, 2) void fused_kernel(
        const float* __restrict__ x, const int* __restrict__ lengths,
        const unsigned short* __restrict__ Wt, const float* __restrict__ bias,
        const float* __restrict__ scale, float* __restrict__ hidden,
        float* __restrict__ tokens) {
    const int b  = blockIdx.y;
    const int t0 = blockIdx.x * 64;
    const int len = lengths[b];
    const int ntok = n_tok_of(len);

    __shared__ unsigned short As[64 * PITCH];    // As[r][k], bf16 (token tile)
    __shared__ unsigned short Bs[512 * PITCH];   // Bs[n][k], bf16 (Wt tile)
    __shared__ float ssbuf[4][64];

    const int tid  = threadIdx.x;
    const int w    = tid >> 6;
    const int lane = tid & 63;
    const int l15  = lane & 15;
    const int quad = lane >> 4;

    f32x4 acc[4][8];                             // [ttile][ctile]
#pragma unroll
    for (int tt = 0; tt < 4; ++tt)
#pragma unroll
        for (int ct = 0; ct < 8; ++ct) acc[tt][ct] = (f32x4){0.f, 0.f, 0.f, 0.f};

    const float* xb   = x + (size_t)b * (Sc * Dc);
    float*       tokb = tokens + (size_t)b * Tc * Kc;

    // Per-thread staging coordinates (A: 2 float4 chunks; B: 8 ushort8 chunks)
    int   a_r[2], a_c[2];  bool a_tv[2];  const float* a_src[2];
#pragma unroll
    for (int it = 0; it < 2; ++it) {
        const int l = tid + it * 256;
        a_r[it] = l >> 3;                        // row in tile (0..63)
        a_c[it] = (l & 7) * 4;                   // k offset within 32-k tile
        const int t = t0 + a_r[it];
        a_tv[it] = (t < Tc);
        a_src[it] = xb + (size_t)t * (STRIDEc * Dc);
    }

    float4  ra[2];
    ushort8 rb[8];

    // ---- prologue loads (k0 = 0) ----
#pragma unroll
    for (int it = 0; it < 2; ++it) {
        const int t = t0 + a_r[it];
        const int kk = a_c[it];
        const int pos = t * STRIDEc + (kk >> 6);
        ra[it] = make_float4(0.f, 0.f, 0.f, 0.f);
        if (a_tv[it] && t < ntok && pos < len) ra[it] = *(const float4*)(a_src[it] + kk);
    }
#pragma unroll
    for (int it = 0; it < 8; ++it)
        rb[it] = *(const ushort8*)(Wt + (size_t)(tid + it * 256) * 8);

    for (int step = 0; step < 16; ++step) {
        const int k0 = step * 32;
        if (step) __syncthreads();               // previous MFMA reads done

        // ---- commit staged regs to LDS (+ tokens out) ----
#pragma unroll
        for (int it = 0; it < 2; ++it) {
            const float4 v = ra[it];
            if (a_tv[it])
                *(float4*)(tokb + (size_t)(t0 + a_r[it]) * Kc + k0 + a_c[it]) = v;
            ushort4 h4;
            h4.x = f2bf(v.x); h4.y = f2bf(v.y); h4.z = f2bf(v.z); h4.w = f2bf(v.w);
            *(ushort4*)(As + a_r[it] * PITCH + a_c[it]) = h4;
        }
#pragma unroll
        for (int it = 0; it < 8; ++it) {
            const int cc = tid + it * 256;
            *(ushort8*)(Bs + (cc >> 2) * PITCH + (cc & 3) * 8) = rb[it];
        }
        __syncthreads();

        // ---- prefetch next tile while MFMA runs ----
        if (step < 15) {
            const int kn = k0 + 32;
#pragma unroll
            for (int it = 0; it < 2; ++it) {
                const int t = t0 + a_r[it];
                const int kk = kn + a_c[it];
                const int pos = t * STRIDEc + (kk >> 6);
                ra[it] = make_float4(0.f, 0.f, 0.f, 0.f);
                if (a_tv[it] && t < ntok && pos < len)
                    ra[it] = *(const float4*)(a_src[it] + kk);
            }
            const unsigned short* wsrc = Wt + (size_t)(step + 1) * (Hc * 32);
#pragma unroll
            for (int it = 0; it < 8; ++it)
                rb[it] = *(const ushort8*)(wsrc + (size_t)(tid + it * 256) * 8);
        }

        // ---- MFMA (operand-swapped) ----
        bf16x8 btok[4];
#pragma unroll
        for (int tt = 0; tt < 4; ++tt)
            btok[tt] = __builtin_bit_cast(bf16x8,
                *(const ushort8*)(As + (tt * 16 + l15) * PITCH + quad * 8));
#pragma unroll
        for (int ct = 0; ct < 8; ++ct) {
            bf16x8 aW = __builtin_bit_cast(bf16x8,
                *(const ushort8*)(Bs + (w * 128 + ct * 16 + l15) * PITCH + quad * 8));
#pragma unroll
            for (int tt = 0; tt < 4; ++tt)
                acc[tt][ct] = __builtin_amdgcn_mfma_f32_16x16x32_bf16(
                    aW, btok[tt], acc[tt][ct], 0, 0, 0);
        }
    }

    // ---- epilogue: bias, in-register row sums, RMS, scale, float4 stores ----
    float ss[4] = {0.f, 0.f, 0.f, 0.f};
#pragma unroll
    for (int ct = 0; ct < 8; ++ct) {
        const f32x4 b4 = *(const f32x4*)(bias + w * 128 + ct * 16 + quad * 4);
#pragma unroll
        for (int tt = 0; tt < 4; ++tt) {
            f32x4 h = acc[tt][ct] + b4;
            acc[tt][ct] = h;
            ss[tt] += h[0] * h[0] + h[1] * h[1] + h[2] * h[2] + h[3] * h[3];
        }
    }
#pragma unroll
    for (int tt = 0; tt < 4; ++tt) {
        float s = ss[tt];
        s += __shfl_xor(s, 16);
        s += __shfl_xor(s, 32);
        if (quad == 0) ssbuf[w][tt * 16 + l15] = s;
    }
    __syncthreads();
    float rstd[4];
#pragma unroll
    for (int tt = 0; tt < 4; ++tt) {
        const int r = tt * 16 + l15;
        const float tot = ssbuf[0][r] + ssbuf[1][r] + ssbuf[2][r] + ssbuf[3][r];
        rstd[tt] = rsqrtf(tot * (1.0f / (float)Hc) + EPSc);
    }
#pragma unroll
    for (int ct = 0; ct < 8; ++ct) {
        const f32x4 s4 = *(const f32x4*)(scale + w * 128 + ct * 16 + quad * 4);
#pragma unroll
        for (int tt = 0; tt < 4; ++tt) {
            const int t = t0 + tt * 16 + l15;
            if (t < Tc) {
                f32x4 o = acc[tt][ct] * rstd[tt] * s4;
                *(f32x4*)(hidden + ((size_t)b * Tc + t) * Hc
                          + w * 128 + ct * 16 + quad * 4) = o;
            }
        }
    }
}

extern "C" void kernel_launch(void* const* d_in, const int* in_sizes, int n_in,
                              void* d_out, int out_size, void* d_ws, size_t ws_size,
                              hipStream_t stream) {
    const float* x       = (const float*)d_in[0];
    const int*   lengths = (const int*)d_in[1];
    const float* W       = (const float*)d_in[2];
    const float* bias    = (const float*)d_in[3];
    const float* scale   = (const float*)d_in[4];

    const size_t BTH = (size_t)Bc * Tc * Hc;   // 16,760,832
    float* out    = (float*)d_out;
    float* hidden = out;                        // output 0
    float* tl     = out + BTH;                  // output 1 (32 floats)
    float* tokens = out + BTH + Bc;             // output 2

    unsigned short* Wt = (unsigned short*)d_ws; // 512x512 bf16 = 512 KB, k-slice-packed

    {   // W -> Wt (transpose + bf16 + slice-pack) and token_lengths
        dim3 grid(Hc / 32, Hc / 32);            // (16,16)
        prep_kernel<<<grid, 256, 0, stream>>>(W, lengths, Wt, tl);
    }
    {   // fused tokens + GEMM + RMSNorm
        dim3 grid(16, Bc);                      // 16 m-blocks x 32 batches
        fused_kernel<<<grid, 256, 0, stream>>>(x, lengths, Wt, bias, scale,
                                               hidden, tokens);
    }
}